// Round 1
// baseline (408.081 us; speedup 1.0000x reference)
//
#include <hip/hip_runtime.h>

#define BB 8
#define NN 8700
#define CC 256
#define QQ 300
#define HH 8
#define DD 32
#define HIDN 1024
#define NSPLIT 8
#define KCHUNK 1088   // ceil(8700/8) rounded to 32

typedef unsigned short u16;
typedef __attribute__((ext_vector_type(8))) short short8;
typedef __attribute__((ext_vector_type(4))) float f32x4;

#define MFMA16(a, b, c) __builtin_amdgcn_mfma_f32_16x16x32_bf16((a), (b), (c), 0, 0, 0)

__device__ __forceinline__ u16 f2bu(float f) {
    unsigned int u = __builtin_bit_cast(unsigned int, f);
    u += 0x7fffu + ((u >> 16) & 1u);   // round-to-nearest-even
    return (u16)(u >> 16);
}

// ---------------- weight prep: f32 [K][N] -> bf16 [N][K] (optionally scaled) ----------------
__global__ __launch_bounds__(256)
void wprep(const float* __restrict__ src, u16* __restrict__ dst, int K, int N, float scale)
{
    int e = blockIdx.x * 256 + threadIdx.x;
    if (e >= K * N) return;
    int n = e / K, kk = e - n * K;
    dst[e] = f2bu(src[(size_t)kk * N + n] * scale);
}

// ---------------- LN1 + context-token output ----------------
// one wave per row; xn (bf16) for GEMMs; for n>=Q: out = 2*(x + g1*xn)
__global__ __launch_bounds__(256)
void ln1_k(const float* __restrict__ x, const float* __restrict__ w,
           const float* __restrict__ bv, const float* __restrict__ g1,
           u16* __restrict__ xn, float* __restrict__ out)
{
    int row = blockIdx.x * 4 + (threadIdx.x >> 6);
    int l = threadIdx.x & 63;
    size_t base = (size_t)row * CC + l * 4;
    float4 xv = *reinterpret_cast<const float4*>(x + base);
    float s  = xv.x + xv.y + xv.z + xv.w;
    float s2 = xv.x * xv.x + xv.y * xv.y + xv.z * xv.z + xv.w * xv.w;
#pragma unroll
    for (int m = 1; m < 64; m <<= 1) {
        s  += __shfl_xor(s,  m, 64);
        s2 += __shfl_xor(s2, m, 64);
    }
    float mean = s * (1.0f / CC);
    float rs = rsqrtf(s2 * (1.0f / CC) - mean * mean + 1e-5f);
    float4 wv = *reinterpret_cast<const float4*>(w  + l * 4);
    float4 bb = *reinterpret_cast<const float4*>(bv + l * 4);
    float n0 = (xv.x - mean) * rs * wv.x + bb.x;
    float n1 = (xv.y - mean) * rs * wv.y + bb.y;
    float n2 = (xv.z - mean) * rs * wv.z + bb.z;
    float n3 = (xv.w - mean) * rs * wv.w + bb.w;
    ushort4 u; u.x = f2bu(n0); u.y = f2bu(n1); u.z = f2bu(n2); u.w = f2bu(n3);
    *reinterpret_cast<ushort4*>(xn + base) = u;
    int n = row % NN;
    if (n >= QQ) {
        float4 gv = *reinterpret_cast<const float4*>(g1 + l * 4);
        float4 o;
        o.x = 2.0f * (xv.x + gv.x * n0);
        o.y = 2.0f * (xv.y + gv.y * n1);
        o.z = 2.0f * (xv.z + gv.z * n2);
        o.w = 2.0f * (xv.w + gv.w * n3);
        *reinterpret_cast<float4*>(out + base) = o;
    }
}

// ---------------- residual + LN2 for query tokens ----------------
__global__ __launch_bounds__(256)
void ln2_k(const float* __restrict__ x, const float* __restrict__ pd,
           const float* __restrict__ g1, const float* __restrict__ w,
           const float* __restrict__ bv, float* __restrict__ xqf, u16* __restrict__ xqb)
{
    int r = blockIdx.x * 4 + (threadIdx.x >> 6);
    int l = threadIdx.x & 63;
    int b = r / QQ, n = r - b * QQ;
    size_t xoff = ((size_t)b * NN + n) * CC + l * 4;
    size_t roff = (size_t)r * CC + l * 4;
    float4 xv = *reinterpret_cast<const float4*>(x + xoff);
    float4 pv = *reinterpret_cast<const float4*>(pd + roff);
    float4 gv = *reinterpret_cast<const float4*>(g1 + l * 4);
    float x0 = xv.x + gv.x * pv.x;
    float x1 = xv.y + gv.y * pv.y;
    float x2 = xv.z + gv.z * pv.z;
    float x3 = xv.w + gv.w * pv.w;
    float s  = x0 + x1 + x2 + x3;
    float s2 = x0 * x0 + x1 * x1 + x2 * x2 + x3 * x3;
#pragma unroll
    for (int m = 1; m < 64; m <<= 1) {
        s  += __shfl_xor(s,  m, 64);
        s2 += __shfl_xor(s2, m, 64);
    }
    float mean = s * (1.0f / CC);
    float rs = rsqrtf(s2 * (1.0f / CC) - mean * mean + 1e-5f);
    float4 wv = *reinterpret_cast<const float4*>(w  + l * 4);
    float4 bb = *reinterpret_cast<const float4*>(bv + l * 4);
    float n0 = (x0 - mean) * rs * wv.x + bb.x;
    float n1 = (x1 - mean) * rs * wv.y + bb.y;
    float n2 = (x2 - mean) * rs * wv.z + bb.z;
    float n3 = (x3 - mean) * rs * wv.w + bb.w;
    float4 o; o.x = n0; o.y = n1; o.z = n2; o.w = n3;
    *reinterpret_cast<float4*>(xqf + roff) = o;
    ushort4 u; u.x = f2bu(n0); u.y = f2bu(n1); u.z = f2bu(n2); u.w = f2bu(n3);
    *reinterpret_cast<ushort4*>(xqb + roff) = u;
}

// ---------------- generic 4-wave MFMA GEMM: C[M,Nout] = A[M,K] @ W[K,Nout] ----------------
// WT is [Nout][K] bf16. Block: 64 rows x 256 cols (wave w owns cols w*64..w*64+63).
// A row r maps to physical row (r/rpb)*bstr + r%rpb.
// EPI: 0 = bf16 store, 1 = exact-GELU -> bf16, 2 = f32 store, 3 = out = base + gvec*acc -> d_out (row remap b*NN + r%QQ)
template<int EPI>
__global__ __launch_bounds__(256)
void gemm_k(const u16* __restrict__ A, const u16* __restrict__ WT,
            u16* __restrict__ Cb, float* __restrict__ Cf,
            const float* __restrict__ basep, const float* __restrict__ gvec,
            float* __restrict__ outp,
            int M, int K, int ldC, int rpb, int bstr)
{
    const int w = threadIdx.x >> 6, l = threadIdx.x & 63;
    const int l15 = l & 15, kg = l >> 4;
    const int rowbase = blockIdx.x * 64;
    const int colbase = blockIdx.y * 256 + w * 64;
    const short8 z8 = {0, 0, 0, 0, 0, 0, 0, 0};
    const f32x4 fz = {0.f, 0.f, 0.f, 0.f};

    const u16* ap[4]; bool av[4];
#pragma unroll
    for (int mi = 0; mi < 4; mi++) {
        int r = rowbase + mi * 16 + l15;
        av[mi] = (r < M);
        int rr = av[mi] ? r : 0;
        size_t ar = (size_t)(rr / rpb) * bstr + (rr % rpb);
        ap[mi] = A + ar * K + kg * 8;
    }
    const u16* bp[4];
#pragma unroll
    for (int ni = 0; ni < 4; ni++) {
        int col = colbase + ni * 16 + l15;
        bp[ni] = WT + (size_t)col * K + kg * 8;
    }
    f32x4 acc[4][4];
#pragma unroll
    for (int mi = 0; mi < 4; mi++)
#pragma unroll
        for (int ni = 0; ni < 4; ni++) acc[mi][ni] = fz;

    for (int ks = 0; ks < K; ks += 32) {
        short8 a[4], bfr[4];
#pragma unroll
        for (int mi = 0; mi < 4; mi++)
            a[mi] = av[mi] ? *reinterpret_cast<const short8*>(ap[mi] + ks) : z8;
#pragma unroll
        for (int ni = 0; ni < 4; ni++)
            bfr[ni] = *reinterpret_cast<const short8*>(bp[ni] + ks);
#pragma unroll
        for (int mi = 0; mi < 4; mi++)
#pragma unroll
            for (int ni = 0; ni < 4; ni++)
                acc[mi][ni] = MFMA16(a[mi], bfr[ni], acc[mi][ni]);
    }
#pragma unroll
    for (int mi = 0; mi < 4; mi++) {
#pragma unroll
        for (int j = 0; j < 4; j++) {
            int r = rowbase + mi * 16 + kg * 4 + j;
            if (r >= M) continue;
#pragma unroll
            for (int ni = 0; ni < 4; ni++) {
                int col = colbase + ni * 16 + l15;
                float v = acc[mi][ni][j];
                if (EPI == 0) {
                    Cb[(size_t)r * ldC + col] = f2bu(v);
                } else if (EPI == 1) {
                    float gl = 0.5f * v * (1.0f + erff(v * 0.70710678118654752f));
                    Cb[(size_t)r * ldC + col] = f2bu(gl);
                } else if (EPI == 2) {
                    Cf[(size_t)r * ldC + col] = v;
                } else {
                    float res = basep[(size_t)r * CC + col] + gvec[col] * v;
                    size_t orow = (size_t)(r / QQ) * NN + (r % QQ);
                    outp[orow * CC + col] = res;
                }
            }
        }
    }
}

// ---------------- flash attention, key-split ----------------
// grid = 64 (b,h) * NSPLIT; block 256 = 4 waves, wave owns 80-query strip.
__global__ __launch_bounds__(256)
void attn_k(const u16* __restrict__ qm, const u16* __restrict__ km,
            const u16* __restrict__ vm, float* __restrict__ Op,
            float* __restrict__ mp, float* __restrict__ lp)
{
    __shared__ u16 kbuf[32][32];
    __shared__ u16 vt[32][32];
    __shared__ u16 plds[4][80][32];
    const int split = blockIdx.x & (NSPLIT - 1);
    const int bh = blockIdx.x >> 3;
    const int b = bh >> 3, h = bh & 7;
    const int w = threadIdx.x >> 6, l = threadIdx.x & 63;
    const int l15 = l & 15, kg = l >> 4;
    const int n0base = split * KCHUNK;
    const int nend = (n0base + KCHUNK < NN) ? (n0base + KCHUNK) : NN;

    const short8 z8 = {0, 0, 0, 0, 0, 0, 0, 0};
    const f32x4 fz = {0.f, 0.f, 0.f, 0.f};

    short8 qf[5];
#pragma unroll
    for (int mf = 0; mf < 5; mf++) {
        int qrow = w * 80 + mf * 16 + l15;
        int qc = qrow < QQ ? qrow : 0;
        short8 v = *reinterpret_cast<const short8*>(qm + ((size_t)(b * QQ + qc) * CC + h * DD + kg * 8));
        qf[mf] = (qrow < QQ) ? v : z8;
    }
    f32x4 o[5][2], mrun[5], lrun[5];
    const f32x4 mninf = {-1e30f, -1e30f, -1e30f, -1e30f};
#pragma unroll
    for (int mf = 0; mf < 5; mf++) {
        o[mf][0] = fz; o[mf][1] = fz; lrun[mf] = fz; mrun[mf] = mninf;
    }

    const int skk = threadIdx.x >> 3;          // staging: key row 0..31
    const int sd4 = (threadIdx.x & 7) * 4;     // staging: d offset

    for (int n0 = n0base; n0 < nend; n0 += 32) {
        int n = n0 + skk;
        if (n < NN) {
            size_t roff = ((size_t)(b * NN + n)) * CC + h * DD + sd4;
            ushort4 kv = *reinterpret_cast<const ushort4*>(km + roff);
            *reinterpret_cast<ushort4*>(&kbuf[skk][sd4]) = kv;
            ushort4 vv = *reinterpret_cast<const ushort4*>(vm + roff);
            vt[sd4 + 0][skk] = vv.x;
            vt[sd4 + 1][skk] = vv.y;
            vt[sd4 + 2][skk] = vv.z;
            vt[sd4 + 3][skk] = vv.w;
        } else {
            ushort4 zz; zz.x = zz.y = zz.z = zz.w = 0;
            *reinterpret_cast<ushort4*>(&kbuf[skk][sd4]) = zz;
            vt[sd4 + 0][skk] = 0; vt[sd4 + 1][skk] = 0;
            vt[sd4 + 2][skk] = 0; vt[sd4 + 3][skk] = 0;
        }
        __syncthreads();

        short8 kb0 = *reinterpret_cast<const short8*>(&kbuf[l15][kg * 8]);
        short8 kb1 = *reinterpret_cast<const short8*>(&kbuf[16 + l15][kg * 8]);
        f32x4 s0[5], s1[5];
#pragma unroll
        for (int mf = 0; mf < 5; mf++) {
            s0[mf] = MFMA16(qf[mf], kb0, fz);
            s1[mf] = MFMA16(qf[mf], kb1, fz);
        }
        if (n0 + 32 > NN) {   // mask out-of-range keys (only last tile of last split)
            bool inv0 = (n0 + l15) >= NN;
            bool inv1 = (n0 + 16 + l15) >= NN;
#pragma unroll
            for (int mf = 0; mf < 5; mf++) {
#pragma unroll
                for (int j = 0; j < 4; j++) {
                    if (inv0) s0[mf][j] = -1e30f;
                    if (inv1) s1[mf][j] = -1e30f;
                }
            }
        }
#pragma unroll
        for (int mf = 0; mf < 5; mf++) {
            float tm[4], al[4], ps[4];
#pragma unroll
            for (int j = 0; j < 4; j++) tm[j] = fmaxf(s0[mf][j], s1[mf][j]);
#pragma unroll
            for (int m = 1; m < 16; m <<= 1) {
#pragma unroll
                for (int j = 0; j < 4; j++) tm[j] = fmaxf(tm[j], __shfl_xor(tm[j], m, 64));
            }
#pragma unroll
            for (int j = 0; j < 4; j++) {
                float mnew = fmaxf(mrun[mf][j], tm[j]);
                al[j] = __expf(mrun[mf][j] - mnew);
                mrun[mf][j] = mnew;
                float p0 = __expf(s0[mf][j] - mnew);
                float p1 = __expf(s1[mf][j] - mnew);
                s0[mf][j] = p0; s1[mf][j] = p1;
                ps[j] = p0 + p1;
            }
#pragma unroll
            for (int m = 1; m < 16; m <<= 1) {
#pragma unroll
                for (int j = 0; j < 4; j++) ps[j] += __shfl_xor(ps[j], m, 64);
            }
#pragma unroll
            for (int j = 0; j < 4; j++) {
                lrun[mf][j] = lrun[mf][j] * al[j] + ps[j];
                o[mf][0][j] *= al[j];
                o[mf][1][j] *= al[j];
                plds[w][mf * 16 + kg * 4 + j][l15]      = f2bu(s0[mf][j]);
                plds[w][mf * 16 + kg * 4 + j][16 + l15] = f2bu(s1[mf][j]);
            }
        }
        __syncthreads();
        short8 vb0 = *reinterpret_cast<const short8*>(&vt[l15][kg * 8]);
        short8 vb1 = *reinterpret_cast<const short8*>(&vt[16 + l15][kg * 8]);
#pragma unroll
        for (int mf = 0; mf < 5; mf++) {
            short8 pa = *reinterpret_cast<const short8*>(&plds[w][mf * 16 + l15][kg * 8]);
            o[mf][0] = MFMA16(pa, vb0, o[mf][0]);
            o[mf][1] = MFMA16(pa, vb1, o[mf][1]);
        }
        __syncthreads();
    }

    size_t pb = (size_t)(split * 64 + bh) * QQ;
#pragma unroll
    for (int mf = 0; mf < 5; mf++) {
#pragma unroll
        for (int j = 0; j < 4; j++) {
            int qrow = w * 80 + mf * 16 + kg * 4 + j;
            if (qrow >= QQ) continue;
            size_t pr = pb + qrow;
            if (l15 == 0) { mp[pr] = mrun[mf][j]; lp[pr] = lrun[mf][j]; }
            Op[pr * DD + l15]      = o[mf][0][j];
            Op[pr * DD + 16 + l15] = o[mf][1][j];
        }
    }
}

// ---------------- combine split partials ----------------
__global__ __launch_bounds__(256)
void comb_k(const float* __restrict__ Op, const float* __restrict__ mp,
            const float* __restrict__ lp, u16* __restrict__ ao)
{
    int g = blockIdx.x * 256 + threadIdx.x;    // 19200 rows * 8 threads
    int d4 = (g & 7) * 4;
    int row = g >> 3;
    int bh = row / QQ, qq = row - bh * QQ;
    int b = bh >> 3, h = bh & 7;
    float ms[NSPLIT], M = -1e30f;
#pragma unroll
    for (int s = 0; s < NSPLIT; s++) {
        ms[s] = mp[(size_t)(s * 64 + bh) * QQ + qq];
        M = fmaxf(M, ms[s]);
    }
    float L = 0.f, a0 = 0.f, a1 = 0.f, a2 = 0.f, a3 = 0.f;
#pragma unroll
    for (int s = 0; s < NSPLIT; s++) {
        size_t pr = (size_t)(s * 64 + bh) * QQ + qq;
        float e = __expf(ms[s] - M);
        L += lp[pr] * e;
        float4 ov = *reinterpret_cast<const float4*>(Op + pr * DD + d4);
        a0 += e * ov.x; a1 += e * ov.y; a2 += e * ov.z; a3 += e * ov.w;
    }
    float inv = 1.0f / L;
    ushort4 u;
    u.x = f2bu(a0 * inv); u.y = f2bu(a1 * inv); u.z = f2bu(a2 * inv); u.w = f2bu(a3 * inv);
    *reinterpret_cast<ushort4*>(ao + ((size_t)(b * QQ + qq) * CC + h * DD + d4)) = u;
}

// ---------------- launch ----------------
extern "C" void kernel_launch(void* const* d_in, const int* in_sizes, int n_in,
                              void* d_out, int out_size, void* d_ws, size_t ws_size,
                              hipStream_t stream)
{
    (void)in_sizes; (void)n_in; (void)out_size; (void)ws_size;
    const float* x    = (const float*)d_in[0];
    const float* Wq   = (const float*)d_in[1];
    const float* Wk   = (const float*)d_in[2];
    const float* Wv   = (const float*)d_in[3];
    const float* Wp   = (const float*)d_in[4];
    const float* W1   = (const float*)d_in[5];
    const float* W2   = (const float*)d_in[6];
    const float* ln1w = (const float*)d_in[7];
    const float* ln1b = (const float*)d_in[8];
    const float* ln2w = (const float*)d_in[9];
    const float* ln2b = (const float*)d_in[10];
    const float* g1   = (const float*)d_in[11];
    const float* g2   = (const float*)d_in[12];
    float* out = (float*)d_out;

    char* p = (char*)d_ws;
    auto alloc = [&](size_t bytes) { char* r = p; p += (bytes + 255) & ~(size_t)255; return r; };

    const size_t MKV = (size_t)BB * NN;        // 69600
    const size_t MQ  = (size_t)BB * QQ;        // 2400

    u16* WqT = (u16*)alloc((size_t)CC * CC * 2);
    u16* WkT = (u16*)alloc((size_t)CC * CC * 2);
    u16* WvT = (u16*)alloc((size_t)CC * CC * 2);
    u16* WpT = (u16*)alloc((size_t)CC * CC * 2);
    u16* W1T = (u16*)alloc((size_t)CC * HIDN * 2);
    u16* W2T = (u16*)alloc((size_t)HIDN * CC * 2);
    u16* xn  = (u16*)alloc(MKV * CC * 2);
    u16* kbf = (u16*)alloc(MKV * CC * 2);
    u16* vbf = (u16*)alloc(MKV * CC * 2);
    u16* qbf = (u16*)alloc(MQ * CC * 2);
    u16* aob = (u16*)alloc(MQ * CC * 2);
    u16* xqb = (u16*)alloc(MQ * CC * 2);
    u16* h1  = (u16*)alloc(MQ * HIDN * 2);
    float* pd  = (float*)alloc(MQ * CC * 4);
    float* xqf = (float*)alloc(MQ * CC * 4);
    float* Op  = (float*)alloc((size_t)NSPLIT * 64 * QQ * DD * 4);
    float* mp  = (float*)alloc((size_t)NSPLIT * 64 * QQ * 4);
    float* lp  = (float*)alloc((size_t)NSPLIT * 64 * QQ * 4);

    const float qscale = 0.17677669529663687f;  // D^-0.5

    // weights -> bf16 transposed
    wprep<<<(CC * CC + 255) / 256, 256, 0, stream>>>(Wq, WqT, CC, CC, qscale);
    wprep<<<(CC * CC + 255) / 256, 256, 0, stream>>>(Wk, WkT, CC, CC, 1.0f);
    wprep<<<(CC * CC + 255) / 256, 256, 0, stream>>>(Wv, WvT, CC, CC, 1.0f);
    wprep<<<(CC * CC + 255) / 256, 256, 0, stream>>>(Wp, WpT, CC, CC, 1.0f);
    wprep<<<(CC * HIDN + 255) / 256, 256, 0, stream>>>(W1, W1T, CC, HIDN, 1.0f);
    wprep<<<(HIDN * CC + 255) / 256, 256, 0, stream>>>(W2, W2T, HIDN, CC, 1.0f);

    // LN1 + context output
    ln1_k<<<(int)(MKV / 4), 256, 0, stream>>>(x, ln1w, ln1b, g1, xn, out);

    // projections
    gemm_k<0><<<dim3(1088, 1), 256, 0, stream>>>(xn, WkT, kbf, nullptr, nullptr, nullptr, nullptr,
                                                 (int)MKV, CC, CC, (int)MKV, 0);
    gemm_k<0><<<dim3(1088, 1), 256, 0, stream>>>(xn, WvT, vbf, nullptr, nullptr, nullptr, nullptr,
                                                 (int)MKV, CC, CC, (int)MKV, 0);
    gemm_k<0><<<dim3(38, 1), 256, 0, stream>>>(xn, WqT, qbf, nullptr, nullptr, nullptr, nullptr,
                                               (int)MQ, CC, CC, QQ, NN);

    // attention (key-split flash) + combine
    attn_k<<<64 * NSPLIT, 256, 0, stream>>>(qbf, kbf, vbf, Op, mp, lp);
    comb_k<<<(int)(MQ * 64 / 256 / 4) * 4 /* 600 */, 256, 0, stream>>>(Op, mp, lp, aob);

    // proj -> f32
    gemm_k<2><<<dim3(38, 1), 256, 0, stream>>>(aob, WpT, nullptr, pd, nullptr, nullptr, nullptr,
                                               (int)MQ, CC, CC, (int)MQ, 0);
    // residual + LN2
    ln2_k<<<(int)(MQ / 4), 256, 0, stream>>>(x, pd, g1, ln2w, ln2b, xqf, xqb);

    // MLP
    gemm_k<1><<<dim3(38, 4), 256, 0, stream>>>(xqb, W1T, h1, nullptr, nullptr, nullptr, nullptr,
                                               (int)MQ, CC, HIDN, (int)MQ, 0);
    gemm_k<3><<<dim3(38, 1), 256, 0, stream>>>(h1, W2T, nullptr, nullptr, xqf, g2, out,
                                               (int)MQ, HIDN, CC, (int)MQ, 0);
}